// Round 6
// baseline (623.542 us; speedup 1.0000x reference)
//
#include <hip/hip_runtime.h>
#include <hip/hip_bf16.h>

typedef short    short8  __attribute__((ext_vector_type(8)));
typedef unsigned uint2v  __attribute__((ext_vector_type(2)));
typedef float    f32x4   __attribute__((ext_vector_type(4)));

#define B_TOT 4096
#define SEQ   256
#define NDOF  7
#define HDIM  256
#define ROWS  8
#define DTF   0.002f

// RNE float->bf16 (setup only)
static __device__ __forceinline__ unsigned short f2bf(float f) {
    union { float f; unsigned u; } u; u.f = f;
    unsigned x = u.u;
    unsigned r = (x + 0x7FFFu + ((x >> 16) & 1u)) >> 16;
    return (unsigned short)r;
}
static __device__ __forceinline__ unsigned cvt_pk_bf16(float lo, float hi) {
    unsigned r;
    asm("v_cvt_pk_bf16_f32 %0, %1, %2" : "=v"(r) : "v"(lo), "v"(hi));
    return r;
}
static __device__ __forceinline__ float silu(float p) {
    return p * __builtin_amdgcn_rcpf(1.0f + __expf(-p));
}

__global__ __launch_bounds__(256, 2)
void NeuralODE_kernel(const float* __restrict__ st0, const float* __restrict__ tq,
                      const float* __restrict__ W1,  const float* __restrict__ b1,
                      const float* __restrict__ W2,  const float* __restrict__ b2,
                      const float* __restrict__ W3,  const float* __restrict__ b3,
                      float* __restrict__ out)
{
    __shared__ __align__(16) short h1b[16 * 264];       // h1 exchange (16 n x 256m + pad)
    __shared__ __align__(16) short xstrip[4 * 16 * 40]; // per-wave x strips
    __shared__ __align__(16) short hstrip[4 * 16 * 72]; // per-wave h2 transpose strips (64+8 pad)
    __shared__ __align__(16) float red[4][16][12];      // L3 partials

    const int tid  = threadIdx.x;
    const int w    = tid >> 6;          // 4 waves
    const int lane = tid & 63;
    const int g    = lane >> 4;
    const int n    = lane & 15;
    const int b0   = blockIdx.x * ROWS;
    const int mb   = 64 * w;            // m-chunk 64 per wave
    const int row  = b0 + (n & 7);      // lanes n>=8 mirror n-8 (bounded, in-range)

    // ---------------- init: zero x strips (k24..39 stay zero forever) ------------
    for (int i = tid; i < 4 * 16 * 40; i += 256) xstrip[i] = 0;

    // ---------------- weight fragments (transposed GEMM; b1 folded at k==7) ------
    short8 a1f[4];
#pragma unroll
    for (int t = 0; t < 4; ++t) {
        short8 fr;
#pragma unroll
        for (int j = 0; j < 8; ++j) {
            int k = 8 * g + j;   // x: 0-6=q, 7=1(bias), 8-14=v, 15=0, 16-22=tau, 23+=0
            int m = mb + 16 * t + n;
            float v;
            if (k < 7)        v = W1[k * HDIM + m];
            else if (k == 7)  v = b1[m];
            else if (k < 15)  v = W1[(k - 1) * HDIM + m];
            else if (k == 15) v = 0.0f;
            else if (k < 23)  v = W1[(k - 2) * HDIM + m];
            else              v = 0.0f;
            fr[j] = (short)f2bf(v);
        }
        a1f[t] = fr;
    }
    short8 a2f[4][8];
#pragma unroll
    for (int t = 0; t < 4; ++t)
#pragma unroll
        for (int ks = 0; ks < 8; ++ks) {
            short8 fr;
#pragma unroll
            for (int j = 0; j < 8; ++j) {
                int k = 32 * ks + 8 * g + j;
                fr[j] = (short)f2bf(W2[(size_t)k * HDIM + mb + 16 * t + n]);
            }
            a2f[t][ks] = fr;
        }
    // W3^T frags for THIS wave's k-slice [64w, 64w+64) (fused L3)
    short8 a3f[2];
#pragma unroll
    for (int s = 0; s < 2; ++s) {
        short8 fr;
#pragma unroll
        for (int j = 0; j < 8; ++j) {
            int k = mb + 32 * s + 8 * g + j;
            fr[j] = (n < NDOF) ? (short)f2bf(W3[k * NDOF + n]) : (short)0;
        }
        a3f[s] = fr;
    }
    f32x4 b2v[4];
#pragma unroll
    for (int t = 0; t < 4; ++t) {
        int m = mb + 16 * t + 4 * g;
        f32x4 tv; tv[0] = b2[m]; tv[1] = b2[m + 1]; tv[2] = b2[m + 2]; tv[3] = b2[m + 3];
        b2v[t] = tv;
    }
    f32x4 c3i;   // b3 folded once (wave 0 only)
#pragma unroll
    for (int r = 0; r < 4; ++r) {
        int m = 4 * g + r;
        c3i[r] = (w == 0 && m < NDOF) ? b3[m] : 0.0f;
    }

    // ---------------- state: lane (g,n), g<2, owns dofs d = 4g+r (= C layout) ----
    f32x4 q, v, a;
    const float* sp = st0 + (size_t)row * 14;
#pragma unroll
    for (int r = 0; r < 4; ++r) {
        int d = 4 * g + r;
        bool val = (g < 2) && (d < NDOF);
        q[r] = val ? sp[d] : 0.0f;
        v[r] = val ? sp[7 + d] : 0.0f;
        a[r] = 0.0f;
    }
    float tn[8];
#pragma unroll
    for (int d = 0; d < 8; ++d) tn[d] = 0.0f;

    const float* tqb = tq + (size_t)row * (SEQ * NDOF);
    auto pf_tau = [&](int idx) {
        if (g == 2) {
            const float* tp = tqb + (size_t)idx * NDOF;
#pragma unroll
            for (int d = 0; d < 7; ++d) tn[d] = tp[d];
        }
    };

    // per-(wave,row) LDS bases
    short* xw  = &xstrip[w * 640 + n * 40];
    short* hw  = &hstrip[w * (16 * 72) + n * 72];
    short* h1w = &h1b[n * 264 + mb];
    const short* h1r = &h1b[n * 264 + 8 * g];

    // x strip write: g0 -> k0..3,8..11 ; g1 -> k4..7,12..15 ; g2 -> k16..23
    auto write_x = [&](f32x4 qn, f32x4 vp) {
        float lo_a = (g == 2) ? tn[0] : qn[0];
        float hi_a = (g == 2) ? tn[1] : qn[1];
        float lo_b = (g == 2) ? tn[2] : qn[2];
        float hi_b = (g == 2) ? tn[3] : ((g == 1) ? 1.0f : qn[3]);   // bias at k==7
        float lo_c = (g == 2) ? tn[4] : vp[0];
        float hi_c = (g == 2) ? tn[5] : vp[1];
        float lo_d = (g == 2) ? tn[6] : vp[2];
        float hi_d = (g == 2) ? 0.0f  : vp[3];
        if (g < 3) {
            int off1 = (g == 2) ? 16 : 4 * g;
            int off2 = off1 + ((g == 2) ? 4 : 8);
            uint2v w1v, w2v;
            w1v[0] = cvt_pk_bf16(lo_a, hi_a); w1v[1] = cvt_pk_bf16(lo_b, hi_b);
            w2v[0] = cvt_pk_bf16(lo_c, hi_c); w2v[1] = cvt_pk_bf16(lo_d, hi_d);
            *(uint2v*)&xw[off1] = w1v;
            *(uint2v*)&xw[off2] = w2v;
        }
    };

    auto accel = [&]() -> f32x4 {
        const f32x4 cz = {0.0f, 0.0f, 0.0f, 0.0f};
        // ---- L1 (intra-wave strip, no barrier) ----
        short8 xf = *(const short8*)&xw[8 * g];
        f32x4 c1[4];
#pragma unroll
        for (int t = 0; t < 4; ++t)
            c1[t] = __builtin_amdgcn_mfma_f32_16x16x32_bf16(a1f[t], xf, cz, 0, 0, 0);
#pragma unroll
        for (int t = 0; t < 4; ++t) {
            uint2v p;
            p[0] = cvt_pk_bf16(silu(c1[t][0]), silu(c1[t][1]));
            p[1] = cvt_pk_bf16(silu(c1[t][2]), silu(c1[t][3]));
            *(uint2v*)&h1w[16 * t + 4 * g] = p;
        }
        __syncthreads();   // B1: h1 complete

        // ---- L2 (4 independent accumulator chains; setprio: blocks are desynced) ----
        f32x4 c2[4];
#pragma unroll
        for (int t = 0; t < 4; ++t) c2[t] = b2v[t];
        __builtin_amdgcn_s_setprio(1);
#pragma unroll
        for (int ks = 0; ks < 8; ++ks) {
            short8 bfr = *(const short8*)&h1r[32 * ks];
#pragma unroll
            for (int t = 0; t < 4; ++t)
                c2[t] = __builtin_amdgcn_mfma_f32_16x16x32_bf16(a2f[t][ks], bfr, c2[t], 0, 0, 0);
        }
        __builtin_amdgcn_s_setprio(0);

        // ---- fused L3: silu -> in-wave transpose strip -> 2 MFMA ----
#pragma unroll
        for (int t = 0; t < 4; ++t) {
            uint2v p;
            p[0] = cvt_pk_bf16(silu(c2[t][0]), silu(c2[t][1]));
            p[1] = cvt_pk_bf16(silu(c2[t][2]), silu(c2[t][3]));
            *(uint2v*)&hw[16 * t + 4 * g] = p;
        }
        short8 p0 = *(const short8*)&hw[8 * g];        // k_local 0..31
        short8 p1 = *(const short8*)&hw[32 + 8 * g];   // k_local 32..63
        f32x4 c3 = __builtin_amdgcn_mfma_f32_16x16x32_bf16(a3f[0], p0, c3i, 0, 0, 0);
        c3 = __builtin_amdgcn_mfma_f32_16x16x32_bf16(a3f[1], p1, c3, 0, 0, 0);
        if (g < 2) *(f32x4*)&red[w][n][4 * g] = c3;
        __syncthreads();   // B2: partials complete

        // ---- reduce 4 partials (g<2 lanes; C layout == state layout) ----
        f32x4 an = cz;
        if (g < 2) {
            const float* rb = &red[0][n][4 * g];
            f32x4 s0 = *(const f32x4*)(rb)       + *(const f32x4*)(rb + 192);
            f32x4 s1 = *(const f32x4*)(rb + 384) + *(const f32x4*)(rb + 576);
            an = s0 + s1;
        }
        return an;
    };

    __syncthreads();   // init (xstrip zeros) visible

    // ---------------- prologue: a0 = accel(x0), tau idx 0 -------------------------
    pf_tau(0);
    write_x(q, v);
    {
        float tt = 1.0f * DTF;
        int ns = (int)floorf(tt / DTF);
        if (ns > SEQ - 1) ns = SEQ - 1;
        pf_tau(ns);
    }
    a = accel();

    // ---------------- 256 Verlet steps --------------------------------------------
    float* op = out + (size_t)(b0 + n) * SEQ * 14;

#pragma unroll 1
    for (int i = 0; i < SEQ; ++i) {
        f32x4 qn, vp;
#pragma unroll
        for (int r = 0; r < 4; ++r) {
            qn[r] = q[r] + v[r] * DTF + a[r] * (0.5f * DTF * DTF);
            vp[r] = v[r] + a[r] * DTF;
        }

        write_x(qn, vp);

        // prefetch tau for next step (exact formula from passing rounds)
        {
            float tt = (float)(i + 2) * DTF;
            int ns = (int)floorf(tt / DTF);
            if (ns > SEQ - 1) ns = SEQ - 1;
            pf_tau(ns);
        }

        f32x4 an = accel();

#pragma unroll
        for (int r = 0; r < 4; ++r)
            v[r] = v[r] + (a[r] + an[r]) * (0.5f * DTF);
        q = qn;
        a = an;

        if (w == 0 && n < 8) {
            float* o = op + (size_t)i * 14;
            if (g == 0) {
                *(f32x4*)(o)     = q;
                *(f32x4*)(o + 7) = v;
            } else if (g == 1) {
                o[4]  = q[0]; o[5]  = q[1]; o[6]  = q[2];
                o[11] = v[0]; o[12] = v[1]; o[13] = v[2];
            }
        }
    }
}

extern "C" void kernel_launch(void* const* d_in, const int* in_sizes, int n_in,
                              void* d_out, int out_size, void* d_ws, size_t ws_size,
                              hipStream_t stream) {
    (void)in_sizes; (void)n_in; (void)d_ws; (void)ws_size; (void)out_size;
    const float* st0 = (const float*)d_in[0];
    const float* tq  = (const float*)d_in[1];
    const float* W1  = (const float*)d_in[2];
    const float* b1  = (const float*)d_in[3];
    const float* W2  = (const float*)d_in[4];
    const float* b2  = (const float*)d_in[5];
    const float* W3  = (const float*)d_in[6];
    const float* b3  = (const float*)d_in[7];

    NeuralODE_kernel<<<dim3(B_TOT / ROWS), dim3(256), 0, stream>>>(
        st0, tq, W1, b1, W2, b2, W3, b3, (float*)d_out);
}

// Round 7
// 478.477 us; speedup vs baseline: 1.3032x; 1.3032x over previous
//
#include <hip/hip_runtime.h>
#include <hip/hip_bf16.h>

typedef short    short8  __attribute__((ext_vector_type(8)));
typedef unsigned uint2v  __attribute__((ext_vector_type(2)));
typedef float    f32x4   __attribute__((ext_vector_type(4)));

#define B_TOT 4096
#define SEQ   256
#define NDOF  7
#define HDIM  256
#define ROWS  16
#define DTF   0.002f

// RNE float->bf16 (setup only)
static __device__ __forceinline__ unsigned short f2bf(float f) {
    union { float f; unsigned u; } u; u.f = f;
    unsigned x = u.u;
    unsigned r = (x + 0x7FFFu + ((x >> 16) & 1u)) >> 16;
    return (unsigned short)r;
}
static __device__ __forceinline__ unsigned cvt_pk_bf16(float lo, float hi) {
    unsigned r;
    asm("v_cvt_pk_bf16_f32 %0, %1, %2" : "=v"(r) : "v"(lo), "v"(hi));
    return r;
}
static __device__ __forceinline__ float silu(float p) {
    return p * __builtin_amdgcn_rcpf(1.0f + __expf(-p));
}

__global__ __launch_bounds__(1024, 4)
void NeuralODE_kernel(const float* __restrict__ st0, const float* __restrict__ tq,
                      const float* __restrict__ W1,  const float* __restrict__ b1,
                      const float* __restrict__ W2,  const float* __restrict__ b2,
                      const float* __restrict__ W3,  const float* __restrict__ b3,
                      float* __restrict__ out)
{
    __shared__ __align__(16) short h1b[16 * 264];        // h1 exchange
    __shared__ __align__(16) short h2b[16 * 264];        // h2 exchange
    __shared__ __align__(16) short xstrip[16 * 16 * 40]; // per-wave x strips
    __shared__ __align__(16) float red[8][16][12];       // L3 partials

    const int tid  = threadIdx.x;
    const int w    = tid >> 6;          // 16 waves
    const int lane = tid & 63;
    const int g    = lane >> 4;
    const int n    = lane & 15;
    const int b0   = blockIdx.x * ROWS;
    const int mb   = 16 * w;            // m-chunk 16 per wave

    // ---------------- init: zero x strips (k24..39 stay zero forever) ------------
    for (int i = tid; i < 16 * 16 * 40; i += 1024) xstrip[i] = 0;

    // ---------------- weight fragments (transposed GEMM; b1 folded at k==7) ------
    short8 a1f;
#pragma unroll
    for (int j = 0; j < 8; ++j) {
        int k = 8 * g + j;   // x: 0-6=q, 7=1(bias), 8-14=v, 15=0, 16-22=tau, 23+=0
        int m = mb + n;
        float v;
        if (k < 7)        v = W1[k * HDIM + m];
        else if (k == 7)  v = b1[m];
        else if (k < 15)  v = W1[(k - 1) * HDIM + m];
        else if (k == 15) v = 0.0f;
        else if (k < 23)  v = W1[(k - 2) * HDIM + m];
        else              v = 0.0f;
        a1f[j] = (short)f2bf(v);
    }
    short8 a2f[8];
#pragma unroll
    for (int ks = 0; ks < 8; ++ks) {
        short8 fr;
#pragma unroll
        for (int j = 0; j < 8; ++j) {
            int k = 32 * ks + 8 * g + j;
            fr[j] = (short)f2bf(W2[(size_t)k * HDIM + mb + n]);
        }
        a2f[ks] = fr;
    }
    // W3^T frag: waves 0..7 own k-slice [32w, 32w+32)
    short8 a3f = {};
    if (w < 8) {
#pragma unroll
        for (int j = 0; j < 8; ++j) {
            int k = 32 * w + 8 * g + j;
            a3f[j] = (n < NDOF) ? (short)f2bf(W3[k * NDOF + n]) : (short)0;
        }
    }
    f32x4 b2v;
    {
        int m = mb + 4 * g;
        b2v[0] = b2[m]; b2v[1] = b2[m + 1]; b2v[2] = b2[m + 2]; b2v[3] = b2[m + 3];
    }
    f32x4 c3i;   // b3 folded once (wave 0 only)
#pragma unroll
    for (int r = 0; r < 4; ++r) {
        int m = 4 * g + r;
        c3i[r] = (w == 0 && m < NDOF) ? b3[m] : 0.0f;
    }

    // ---------------- state: lane (g,n), g<2, owns dofs d = 4g+r (= C layout) ----
    f32x4 q, v, a;
    const float* sp = st0 + (size_t)(b0 + n) * 14;
#pragma unroll
    for (int r = 0; r < 4; ++r) {
        int d = 4 * g + r;
        bool val = (g < 2) && (d < NDOF);
        q[r] = val ? sp[d] : 0.0f;
        v[r] = val ? sp[7 + d] : 0.0f;
        a[r] = 0.0f;
    }
    float tn[8];
#pragma unroll
    for (int d = 0; d < 8; ++d) tn[d] = 0.0f;

    const float* tqb = tq + (size_t)(b0 + n) * (SEQ * NDOF);
    auto pf_tau = [&](int idx) {
        if (g == 2) {
            const float* tp = tqb + (size_t)idx * NDOF;
#pragma unroll
            for (int d = 0; d < 7; ++d) tn[d] = tp[d];
        }
    };

    // per-(wave,row) LDS bases
    short* xw  = &xstrip[w * 640 + n * 40];
    short* h1w = &h1b[n * 264 + mb];
    short* h2w = &h2b[n * 264 + mb];
    const short* h1r = &h1b[n * 264 + 8 * g];

    // x strip write: g0 -> k0..3,8..11 ; g1 -> k4..7,12..15 ; g2 -> k16..23
    auto write_x = [&](f32x4 qn, f32x4 vp) {
        float lo_a = (g == 2) ? tn[0] : qn[0];
        float hi_a = (g == 2) ? tn[1] : qn[1];
        float lo_b = (g == 2) ? tn[2] : qn[2];
        float hi_b = (g == 2) ? tn[3] : ((g == 1) ? 1.0f : qn[3]);   // bias at k==7
        float lo_c = (g == 2) ? tn[4] : vp[0];
        float hi_c = (g == 2) ? tn[5] : vp[1];
        float lo_d = (g == 2) ? tn[6] : vp[2];
        float hi_d = (g == 2) ? 0.0f  : vp[3];
        if (g < 3) {
            int off1 = (g == 2) ? 16 : 4 * g;
            int off2 = off1 + ((g == 2) ? 4 : 8);
            uint2v w1v, w2v;
            w1v[0] = cvt_pk_bf16(lo_a, hi_a); w1v[1] = cvt_pk_bf16(lo_b, hi_b);
            w2v[0] = cvt_pk_bf16(lo_c, hi_c); w2v[1] = cvt_pk_bf16(lo_d, hi_d);
            *(uint2v*)&xw[off1] = w1v;
            *(uint2v*)&xw[off2] = w2v;
        }
    };

    auto accel = [&]() -> f32x4 {
        const f32x4 cz = {0.0f, 0.0f, 0.0f, 0.0f};
        // ---- L1 (intra-wave strip, no barrier) ----
        short8 xf = *(const short8*)&xw[8 * g];
        f32x4 c1 = __builtin_amdgcn_mfma_f32_16x16x32_bf16(a1f, xf, cz, 0, 0, 0);
        {
            uint2v p;
            p[0] = cvt_pk_bf16(silu(c1[0]), silu(c1[1]));
            p[1] = cvt_pk_bf16(silu(c1[2]), silu(c1[3]));
            *(uint2v*)&h1w[4 * g] = p;
        }
        __syncthreads();   // B1: h1 complete

        // ---- L2 (two independent accumulator chains) ----
        f32x4 c2e = b2v, c2o = cz;
        __builtin_amdgcn_s_setprio(1);
#pragma unroll
        for (int ks = 0; ks < 4; ++ks) {
            short8 be = *(const short8*)&h1r[32 * ks];
            short8 bo = *(const short8*)&h1r[32 * (ks + 4)];
            c2e = __builtin_amdgcn_mfma_f32_16x16x32_bf16(a2f[ks], be, c2e, 0, 0, 0);
            c2o = __builtin_amdgcn_mfma_f32_16x16x32_bf16(a2f[ks + 4], bo, c2o, 0, 0, 0);
        }
        __builtin_amdgcn_s_setprio(0);
        f32x4 c2 = c2e + c2o;
        {
            uint2v p;
            p[0] = cvt_pk_bf16(silu(c2[0]), silu(c2[1]));
            p[1] = cvt_pk_bf16(silu(c2[2]), silu(c2[3]));
            *(uint2v*)&h2w[4 * g] = p;
        }
        __syncthreads();   // B2: h2 complete

        // ---- L3: waves 0..7 each compute K=32 partial ----
        if (w < 8) {
            short8 pfr = *(const short8*)&h2b[n * 264 + 32 * w + 8 * g];
            f32x4 c3 = __builtin_amdgcn_mfma_f32_16x16x32_bf16(a3f, pfr, c3i, 0, 0, 0);
            if (g < 2) *(f32x4*)&red[w][n][4 * g] = c3;
        }
        __syncthreads();   // B3: partials complete

        // ---- reduce 8 partials (g<2 lanes; C layout == state layout) ----
        f32x4 an = cz;
        if (g < 2) {
            const float* rb = &red[0][n][4 * g];
            f32x4 s0 = *(const f32x4*)(rb)        + *(const f32x4*)(rb + 192);
            f32x4 s1 = *(const f32x4*)(rb + 384)  + *(const f32x4*)(rb + 576);
            f32x4 s2 = *(const f32x4*)(rb + 768)  + *(const f32x4*)(rb + 960);
            f32x4 s3 = *(const f32x4*)(rb + 1152) + *(const f32x4*)(rb + 1344);
            an = (s0 + s1) + (s2 + s3);
        }
        return an;
    };

    __syncthreads();   // init (xstrip zeros) visible

    // ---------------- prologue: a0 = accel(x0), tau idx 0 -------------------------
    pf_tau(0);
    write_x(q, v);
    {
        float tt = 1.0f * DTF;
        int ns = (int)floorf(tt / DTF);
        if (ns > SEQ - 1) ns = SEQ - 1;
        pf_tau(ns);
    }
    a = accel();

    // ---------------- 256 Verlet steps --------------------------------------------
    float* op = out + (size_t)(b0 + n) * SEQ * 14;

#pragma unroll 1
    for (int i = 0; i < SEQ; ++i) {
        f32x4 qn, vp;
#pragma unroll
        for (int r = 0; r < 4; ++r) {
            qn[r] = q[r] + v[r] * DTF + a[r] * (0.5f * DTF * DTF);
            vp[r] = v[r] + a[r] * DTF;
        }

        write_x(qn, vp);

        // prefetch tau for next step (exact formula from passing rounds)
        {
            float tt = (float)(i + 2) * DTF;
            int ns = (int)floorf(tt / DTF);
            if (ns > SEQ - 1) ns = SEQ - 1;
            pf_tau(ns);
        }

        f32x4 an = accel();

#pragma unroll
        for (int r = 0; r < 4; ++r)
            v[r] = v[r] + (a[r] + an[r]) * (0.5f * DTF);
        q = qn;
        a = an;

        if (w == 0) {
            float* o = op + (size_t)i * 14;
            if (g == 0) {
                *(f32x4*)(o)     = q;
                *(f32x4*)(o + 7) = v;
            } else if (g == 1) {
                o[4]  = q[0]; o[5]  = q[1]; o[6]  = q[2];
                o[11] = v[0]; o[12] = v[1]; o[13] = v[2];
            }
        }
    }
}

extern "C" void kernel_launch(void* const* d_in, const int* in_sizes, int n_in,
                              void* d_out, int out_size, void* d_ws, size_t ws_size,
                              hipStream_t stream) {
    (void)in_sizes; (void)n_in; (void)d_ws; (void)ws_size; (void)out_size;
    const float* st0 = (const float*)d_in[0];
    const float* tq  = (const float*)d_in[1];
    const float* W1  = (const float*)d_in[2];
    const float* b1  = (const float*)d_in[3];
    const float* W2  = (const float*)d_in[4];
    const float* b2  = (const float*)d_in[5];
    const float* W3  = (const float*)d_in[6];
    const float* b3  = (const float*)d_in[7];

    NeuralODE_kernel<<<dim3(B_TOT / ROWS), dim3(1024), 0, stream>>>(
        st0, tq, W1, b1, W2, b2, W3, b3, (float*)d_out);
}

// Round 8
// 402.420 us; speedup vs baseline: 1.5495x; 1.1890x over previous
//
#include <hip/hip_runtime.h>
#include <hip/hip_bf16.h>

typedef short    short8  __attribute__((ext_vector_type(8)));
typedef short    short4v __attribute__((ext_vector_type(4)));
typedef unsigned uint2v  __attribute__((ext_vector_type(2)));
typedef float    f32x4   __attribute__((ext_vector_type(4)));

#define B_TOT 4096
#define SEQ   256
#define NDOF  7
#define HDIM  256
#define ROWS  16
#define DTF   0.002f

// RNE float->bf16 (setup only)
static __device__ __forceinline__ unsigned short f2bf(float f) {
    union { float f; unsigned u; } u; u.f = f;
    unsigned x = u.u;
    unsigned r = (x + 0x7FFFu + ((x >> 16) & 1u)) >> 16;
    return (unsigned short)r;
}
static __device__ __forceinline__ unsigned cvt_pk_bf16(float lo, float hi) {
    unsigned r;
    asm("v_cvt_pk_bf16_f32 %0, %1, %2" : "=v"(r) : "v"(lo), "v"(hi));
    return r;
}
static __device__ __forceinline__ float silu(float p) {
    return p * __builtin_amdgcn_rcpf(1.0f + __expf(-p));
}

__global__ __launch_bounds__(512, 2)
void NeuralODE_kernel(const float* __restrict__ st0, const float* __restrict__ tq,
                      const float* __restrict__ W1,  const float* __restrict__ b1,
                      const float* __restrict__ W2,  const float* __restrict__ b2,
                      const float* __restrict__ W3,  const float* __restrict__ b3,
                      float* __restrict__ out)
{
    __shared__ __align__(16) short h1b[16 * 264];
    __shared__ __align__(16) short h2b[16 * 264];
    __shared__ __align__(16) short taub[SEQ * 16 * 8];   // [s][row][8] bf16, d=7 zero pad
    __shared__ __align__(16) short xstrip[8 * 16 * 40];  // per-wave x~ strip: [n][40] bf16
    __shared__ __align__(16) float red[4][16][12];       // L3 partials

    const int tid  = threadIdx.x;
    const int w    = tid >> 6;          // 8 waves
    const int lane = tid & 63;
    const int g    = lane >> 4;
    const int n    = lane & 15;
    const int b0   = blockIdx.x * ROWS;
    const int mb   = 32 * w;

    // ---------------- init: zero strips, fill tau cache -----------------------
    for (int i = tid; i < 8 * 16 * 40; i += 512) xstrip[i] = 0;
    for (int i = tid; i < SEQ * ROWS; i += 512) taub[i * 8 + 7] = 0;
    for (int it = tid; it < ROWS * SEQ * NDOF; it += 512) {
        int row = it / (SEQ * NDOF);
        int off = it - row * (SEQ * NDOF);
        int s   = off / NDOF;
        int d   = off - s * NDOF;
        taub[s * 128 + row * 8 + d] = (short)f2bf(tq[(size_t)(b0 + row) * (SEQ * NDOF) + off]);
    }

    // ---------------- fused small-matrix frags (x~ = [q,1,w,0,a,0,tau,0], K=32) --
    // p1 = A q + b1 + E w + G a + C tau ; E = A*dt + B, G = (dt/2)*B
    auto mk_small = [&](float alpha, float beta, short8* fr2) {
#pragma unroll
        for (int t = 0; t < 2; ++t) {
            short8 fr;
#pragma unroll
            for (int j = 0; j < 8; ++j) {
                int k = 8 * g + j;
                int m = mb + 16 * t + n;
                float v;
                if (k < 7)        v = W1[k * HDIM + m];                          // A
                else if (k == 7)  v = b1[m];                                     // bias
                else if (k < 15)  v = W1[(k - 8) * HDIM + m] * alpha
                                    + W1[(k - 1) * HDIM + m];                    // E (or B)
                else if (k == 15) v = 0.0f;
                else if (k < 23)  v = beta * W1[(k - 9) * HDIM + m];             // G: (7+(k-16))=k-9
                else if (k == 23) v = 0.0f;
                else if (k < 31)  v = W1[(k - 10) * HDIM + m];                   // C: 14+(k-24)
                else              v = 0.0f;
                fr[j] = (short)f2bf(v);
            }
            fr2[t] = fr;
        }
    };
    short8 s0f[2], sxf[2];
    mk_small(0.0f, 0.0f, s0f);                 // prologue: [A|b1|B|0|0|0|C|0]
    mk_small(DTF, 0.5f * DTF, sxf);            // steady:   [A|b1|E|0|G|0|C|0]

    short8 a2f[2][8];
#pragma unroll
    for (int t = 0; t < 2; ++t)
#pragma unroll
        for (int ks = 0; ks < 8; ++ks) {
            short8 fr;
#pragma unroll
            for (int j = 0; j < 8; ++j) {
                int k = 32 * ks + 8 * g + j;
                fr[j] = (short)f2bf(W2[(size_t)k * HDIM + mb + 16 * t + n]);
            }
            a2f[t][ks] = fr;
        }
    short8 a3f[2] = {};
    if (w < 4) {
#pragma unroll
        for (int s = 0; s < 2; ++s) {
            short8 fr;
#pragma unroll
            for (int j = 0; j < 8; ++j) {
                int k = 64 * w + 32 * s + 8 * g + j;
                fr[j] = (n < NDOF) ? (short)f2bf(W3[k * NDOF + n]) : (short)0;
            }
            a3f[s] = fr;
        }
    }
    f32x4 b2v[2];
#pragma unroll
    for (int t = 0; t < 2; ++t) {
        int m = mb + 16 * t + 4 * g;
        f32x4 tv; tv[0] = b2[m]; tv[1] = b2[m + 1]; tv[2] = b2[m + 2]; tv[3] = b2[m + 3];
        b2v[t] = tv;
    }
    f32x4 b3v;
#pragma unroll
    for (int r = 0; r < 4; ++r) {
        int m = 4 * g + r;
        b3v[r] = (m < NDOF) ? b3[m] : 0.0f;
    }

    // ---------------- state (g<2 lanes own dofs d = 4g+r): q and half-kick w ----
    f32x4 q, wv;
    const float* sp = st0 + (size_t)(b0 + n) * 14;
#pragma unroll
    for (int r = 0; r < 4; ++r) {
        int d = 4 * g + r;
        bool val = (g < 2) && (d < NDOF);
        q[r]  = val ? sp[d] : 0.0f;
        wv[r] = val ? sp[7 + d] : 0.0f;   // holds v0 initially
    }

    short* xw  = &xstrip[w * 640 + n * 40];
    short* h1w = &h1b[n * 264 + mb];
    short* h2w = &h2b[n * 264 + mb];
    const short* h1r = &h1b[n * 264 + 8 * g];

    auto wr_q = [&](f32x4 qv) {
        if (g == 0) {
            uint2v p; p[0] = cvt_pk_bf16(qv[0], qv[1]); p[1] = cvt_pk_bf16(qv[2], qv[3]);
            *(uint2v*)&xw[0] = p;
        } else if (g == 1) {
            uint2v p; p[0] = cvt_pk_bf16(qv[0], qv[1]); p[1] = cvt_pk_bf16(qv[2], 1.0f);
            *(uint2v*)&xw[4] = p;
        }
    };
    auto wr_w = [&](f32x4 x) {
        if (g == 0) {
            uint2v p; p[0] = cvt_pk_bf16(x[0], x[1]); p[1] = cvt_pk_bf16(x[2], x[3]);
            *(uint2v*)&xw[8] = p;
        } else if (g == 1) {
            uint2v p; p[0] = cvt_pk_bf16(x[0], x[1]); p[1] = cvt_pk_bf16(x[2], 0.0f);
            *(uint2v*)&xw[12] = p;
        }
    };
    auto wr_a = [&](f32x4 x) {
        if (g == 0) {
            uint2v p; p[0] = cvt_pk_bf16(x[0], x[1]); p[1] = cvt_pk_bf16(x[2], x[3]);
            *(uint2v*)&xw[16] = p;
        } else if (g == 1) {
            uint2v p; p[0] = cvt_pk_bf16(x[0], x[1]); p[1] = cvt_pk_bf16(x[2], 0.0f);
            *(uint2v*)&xw[20] = p;
        }
    };
    auto wr_tau = [&](int idx) {
        if (g == 2)
            *(short8*)&xw[24] = *(const short8*)&taub[idx * 128 + n * 8];
    };

    // accel body: consumes pre-read xf, returns a (valid in g<2 lanes)
    auto accel = [&](short8 xf, const short8* sf) -> f32x4 {
        const f32x4 cz = {0.0f, 0.0f, 0.0f, 0.0f};
        f32x4 c1a = __builtin_amdgcn_mfma_f32_16x16x32_bf16(sf[0], xf, cz, 0, 0, 0);
        f32x4 c1b = __builtin_amdgcn_mfma_f32_16x16x32_bf16(sf[1], xf, cz, 0, 0, 0);
        {
            uint2v p;
            p[0] = cvt_pk_bf16(silu(c1a[0]), silu(c1a[1]));
            p[1] = cvt_pk_bf16(silu(c1a[2]), silu(c1a[3]));
            *(uint2v*)&h1w[4 * g] = p;
            p[0] = cvt_pk_bf16(silu(c1b[0]), silu(c1b[1]));
            p[1] = cvt_pk_bf16(silu(c1b[2]), silu(c1b[3]));
            *(uint2v*)&h1w[16 + 4 * g] = p;
        }
        __syncthreads();   // B1

        f32x4 c2a = b2v[0], c2b = b2v[1];
#pragma unroll
        for (int ks = 0; ks < 8; ++ks) {
            short8 bfr = *(const short8*)&h1r[32 * ks];
            c2a = __builtin_amdgcn_mfma_f32_16x16x32_bf16(a2f[0][ks], bfr, c2a, 0, 0, 0);
            c2b = __builtin_amdgcn_mfma_f32_16x16x32_bf16(a2f[1][ks], bfr, c2b, 0, 0, 0);
        }
        {
            uint2v p;
            p[0] = cvt_pk_bf16(silu(c2a[0]), silu(c2a[1]));
            p[1] = cvt_pk_bf16(silu(c2a[2]), silu(c2a[3]));
            *(uint2v*)&h2w[4 * g] = p;
            p[0] = cvt_pk_bf16(silu(c2b[0]), silu(c2b[1]));
            p[1] = cvt_pk_bf16(silu(c2b[2]), silu(c2b[3]));
            *(uint2v*)&h2w[16 + 4 * g] = p;
        }
        __syncthreads();   // B2

        if (w < 4) {
            short8 p0 = *(const short8*)&h2b[n * 264 + 64 * w + 8 * g];
            short8 p1 = *(const short8*)&h2b[n * 264 + 64 * w + 32 + 8 * g];
            f32x4 ci = (w == 0) ? b3v : cz;
            f32x4 c3 = __builtin_amdgcn_mfma_f32_16x16x32_bf16(a3f[0], p0, ci, 0, 0, 0);
            c3 = __builtin_amdgcn_mfma_f32_16x16x32_bf16(a3f[1], p1, c3, 0, 0, 0);
            if (g < 2) *(f32x4*)&red[w][n][4 * g] = c3;
        }
        __syncthreads();   // B3

        f32x4 an = cz;
        if (g < 2) {
            const float* rb = &red[0][n][4 * g];
            f32x4 s0 = *(const f32x4*)(rb)       + *(const f32x4*)(rb + 192);
            f32x4 s1 = *(const f32x4*)(rb + 384) + *(const f32x4*)(rb + 576);
            an = s0 + s1;
        }
        return an;
    };

    __syncthreads();   // init (strips + taub) visible

    // ---------------- prologue: eval 0 with S0 = [A|b1|B|0|0|0|C|0] -------------
    wr_q(q);
    wr_w(wv);          // w-channel carries v0 for eval 0
    wr_tau(0);
    {
        short8 xf0 = *(const short8*)&xw[8 * g];
        f32x4 a0 = accel(xf0, s0f);
#pragma unroll
        for (int r = 0; r < 4; ++r) wv[r] = wv[r] + (0.5f * DTF) * a0[r];   // w0 = v0 + dt/2 a0
        wr_w(wv);
        wr_a(a0);
        wr_tau(1);     // idx(1) = 1
    }

    // ---------------- 256 steps: eval e = 1..256 --------------------------------
    float* op = out + (size_t)(b0 + n) * SEQ * 14;

#pragma unroll 1
    for (int e = 1; e <= SEQ; ++e) {
        short8 xf = *(const short8*)&xw[8 * g];   // x~_e (read before overwriting)

        // top (off critical path): q_e = q_{e-1} + dt*w_{e-1}; prewrite q & tau
        f32x4 qn;
#pragma unroll
        for (int r = 0; r < 4; ++r) qn[r] = q[r] + DTF * wv[r];
        wr_q(qn);
        {
            float tt = (float)(e + 1) * DTF;
            int ns = (int)floorf(tt / DTF);
            if (ns > SEQ - 1) ns = SEQ - 1;
            wr_tau(ns);
        }

        f32x4 an = accel(xf, sxf);

        // tail: w_e = w + dt*a_e ; v_e = w_{e-1} + dt/2 a_e ; write w,a channels
        f32x4 vo;
#pragma unroll
        for (int r = 0; r < 4; ++r) {
            vo[r] = wv[r] + (0.5f * DTF) * an[r];
            wv[r] = wv[r] + DTF * an[r];
        }
        wr_w(wv);
        wr_a(an);

        if (w == 0) {
            float* o = op + (size_t)(e - 1) * 14;
            if (g == 0) {
                *(f32x4*)(o)     = qn;
                *(f32x4*)(o + 7) = vo;
            } else if (g == 1) {
                o[4]  = qn[0]; o[5]  = qn[1]; o[6]  = qn[2];
                o[11] = vo[0]; o[12] = vo[1]; o[13] = vo[2];
            }
        }
        q = qn;
    }
}

extern "C" void kernel_launch(void* const* d_in, const int* in_sizes, int n_in,
                              void* d_out, int out_size, void* d_ws, size_t ws_size,
                              hipStream_t stream) {
    (void)in_sizes; (void)n_in; (void)d_ws; (void)ws_size; (void)out_size;
    const float* st0 = (const float*)d_in[0];
    const float* tq  = (const float*)d_in[1];
    const float* W1  = (const float*)d_in[2];
    const float* b1  = (const float*)d_in[3];
    const float* W2  = (const float*)d_in[4];
    const float* b2  = (const float*)d_in[5];
    const float* W3  = (const float*)d_in[6];
    const float* b3  = (const float*)d_in[7];

    NeuralODE_kernel<<<dim3(B_TOT / ROWS), dim3(512), 0, stream>>>(
        st0, tq, W1, b1, W2, b2, W3, b3, (float*)d_out);
}